// Round 1
// baseline (841.485 us; speedup 1.0000x reference)
//
#include <hip/hip_runtime.h>
#include <hip/hip_bf16.h>
#include <math.h>

#define B_ 2048
#define D_ 512
#define V_ 100000
#define BM 128
#define BN 128
#define BK 64
#define NCT 782   // ceil(100000/128)

constexpr float S_SCALE = 64.0f;
constexpr float COS_M_ = 0.8775825618903728f;   // cos(0.5)
constexpr float SIN_M_ = 0.479425538604203f;    // sin(0.5)
constexpr float MM_    = 0.2397127693021015f;   // sin(0.5)*0.5
constexpr float THRESH = -0.8775825618903728f;  // cos(pi-0.5)

typedef __attribute__((ext_vector_type(8))) short short8;
typedef __attribute__((ext_vector_type(4))) float f32x4;

__device__ __forceinline__ unsigned short f2bf(float x) {
    __hip_bfloat16 h = __float2bfloat16(x);
    unsigned short u;
    __builtin_memcpy(&u, &h, 2);
    return u;
}

// swizzled ushort index within a [128][64] bf16 LDS tile: byte ^= ((row&7)<<4)
__device__ __forceinline__ int swz(int row, int col) {
    return (row * BK + col) ^ ((row & 7) << 3);
}

// ---------------- K1: normalize embeddings -> bf16, store rnorm_e ----------------
__global__ void k_norm_e(const float* __restrict__ e, unsigned short* __restrict__ ebf,
                         float* __restrict__ rne) {
    int row = blockIdx.x * 4 + (threadIdx.x >> 6);
    int lane = threadIdx.x & 63;
    const float4* src = (const float4*)(e + (size_t)row * D_);
    float4 a = src[lane];
    float4 b = src[lane + 64];
    float ss = a.x*a.x + a.y*a.y + a.z*a.z + a.w*a.w
             + b.x*b.x + b.y*b.y + b.z*b.z + b.w*b.w;
    #pragma unroll
    for (int d = 1; d < 64; d <<= 1) ss += __shfl_xor(ss, d, 64);
    float rn = 1.0f / fmaxf(sqrtf(ss), 1e-12f);
    ushort4* dst = (ushort4*)(ebf + (size_t)row * D_);
    dst[lane]      = make_ushort4(f2bf(a.x*rn), f2bf(a.y*rn), f2bf(a.z*rn), f2bf(a.w*rn));
    dst[lane + 64] = make_ushort4(f2bf(b.x*rn), f2bf(b.y*rn), f2bf(b.z*rn), f2bf(b.w*rn));
    if (lane == 0) rne[row] = rn;
}

// ---------------- K2: weight row rnorms ----------------
__global__ void k_norm_w(const float* __restrict__ w, float* __restrict__ rnw) {
    int row = blockIdx.x * 4 + (threadIdx.x >> 6);
    int lane = threadIdx.x & 63;
    const float4* src = (const float4*)(w + (size_t)row * D_);
    float4 a = src[lane];
    float4 b = src[lane + 64];
    float ss = a.x*a.x + a.y*a.y + a.z*a.z + a.w*a.w
             + b.x*b.x + b.y*b.y + b.z*b.z + b.w*b.w;
    #pragma unroll
    for (int d = 1; d < 64; d <<= 1) ss += __shfl_xor(ss, d, 64);
    if (lane == 0) rnw[row] = 1.0f / fmaxf(sqrtf(ss), 1e-12f);
}

// combine two online-softmax states, -inf-safe
__device__ __forceinline__ void sm_combine(float& m, float& s, float om, float os) {
    float M = fmaxf(m, om);
    float ns = ((m  == -INFINITY) ? 0.0f : s  * __expf(m  - M))
             + ((om == -INFINITY) ? 0.0f : os * __expf(om - M));
    m = M; s = ns;
}

// ---------------- K3: fused GEMM + ArcFace + per-tile logsumexp partials ----------------
__global__ __launch_bounds__(256) void k_gemm(const unsigned short* __restrict__ ebf,
                                              const float* __restrict__ w,
                                              const float* __restrict__ rnw,
                                              float2* __restrict__ partials) {
    const int rt = blockIdx.x;         // 16 row tiles
    const int ct = blockIdx.y;         // 782 col tiles
    const int row0 = rt * BM, n0 = ct * BN;
    const int tid = threadIdx.x, lane = tid & 63, wid = tid >> 6;
    const int wm = wid >> 1, wn = wid & 1;

    __shared__ unsigned short As[BM * BK];  // 16KB swizzled
    __shared__ unsigned short Bs[BN * BK];  // 16KB swizzled
    __shared__ float redm[2][BM], reds[2][BM];

    f32x4 acc[4][4];
    #pragma unroll
    for (int i = 0; i < 4; ++i)
        #pragma unroll
        for (int j = 0; j < 4; ++j)
            acc[i][j] = (f32x4){0.f, 0.f, 0.f, 0.f};

    for (int ks = 0; ks < D_ / BK; ++ks) {
        const int kk = ks * BK;
        // stage A: 128x64 bf16 from normalized embeddings
        #pragma unroll
        for (int p = 0; p < 4; ++p) {
            int idx = p * 256 + tid;
            int r = idx >> 3;
            int c = (idx & 7) * 8;
            uint4 val = *(const uint4*)(ebf + (size_t)(row0 + r) * D_ + kk + c);
            *(uint4*)(As + swz(r, c)) = val;
        }
        // stage B: 128x64 f32 weight -> normalized bf16
        #pragma unroll
        for (int p = 0; p < 4; ++p) {
            int idx = p * 256 + tid;
            int r = idx >> 3;
            int c = (idx & 7) * 8;
            int gr = n0 + r;
            uint4 val;
            if (gr < V_) {
                float rn = rnw[gr];
                const float4* src = (const float4*)(w + (size_t)gr * D_ + kk + c);
                float4 f0 = src[0], f1 = src[1];
                val.x = (unsigned)f2bf(f0.x*rn) | ((unsigned)f2bf(f0.y*rn) << 16);
                val.y = (unsigned)f2bf(f0.z*rn) | ((unsigned)f2bf(f0.w*rn) << 16);
                val.z = (unsigned)f2bf(f1.x*rn) | ((unsigned)f2bf(f1.y*rn) << 16);
                val.w = (unsigned)f2bf(f1.z*rn) | ((unsigned)f2bf(f1.w*rn) << 16);
            } else {
                val = make_uint4(0, 0, 0, 0);
            }
            *(uint4*)(Bs + swz(r, c)) = val;
        }
        __syncthreads();
        #pragma unroll
        for (int kc = 0; kc < 2; ++kc) {
            const int kbase = kc * 32 + (lane >> 4) * 8;
            short8 af[4], bfr[4];
            #pragma unroll
            for (int mf = 0; mf < 4; ++mf) {
                int r = wm * 64 + mf * 16 + (lane & 15);
                af[mf] = *(const short8*)(As + swz(r, kbase));
            }
            #pragma unroll
            for (int nf = 0; nf < 4; ++nf) {
                int r = wn * 64 + nf * 16 + (lane & 15);
                bfr[nf] = *(const short8*)(Bs + swz(r, kbase));
            }
            #pragma unroll
            for (int mf = 0; mf < 4; ++mf)
                #pragma unroll
                for (int nf = 0; nf < 4; ++nf)
                    acc[mf][nf] = __builtin_amdgcn_mfma_f32_16x16x32_bf16(af[mf], bfr[nf], acc[mf][nf], 0, 0, 0);
        }
        __syncthreads();
    }

    // epilogue: ArcFace transform + per-row online (max,sumexp) over this tile's 128 cols
    #pragma unroll
    for (int mf = 0; mf < 4; ++mf) {
        #pragma unroll
        for (int r = 0; r < 4; ++r) {
            float vmax = -INFINITY, vsum = 0.0f;
            #pragma unroll
            for (int nf = 0; nf < 4; ++nf) {
                float cth = acc[mf][nf][r];
                int coltile = wn * 64 + nf * 16 + (lane & 15);
                bool valid = (n0 + coltile) < V_;
                cth = fminf(fmaxf(cth, -1.0f), 1.0f);
                float sth = sqrtf(fmaxf(1.0f - cth * cth, 0.0f));
                float cm = cth * COS_M_ - sth * SIN_M_;
                cm = (cth > THRESH) ? cm : (cth - MM_);
                float lg = cm * S_SCALE;
                if (valid) {
                    if (lg > vmax) { vsum = vsum * __expf(vmax - lg) + 1.0f; vmax = lg; }
                    else           { vsum += __expf(lg - vmax); }
                }
            }
            // reduce across the 16 lanes holding this row's columns
            #pragma unroll
            for (int d = 1; d < 16; d <<= 1) {
                float om = __shfl_xor(vmax, d, 64);
                float os = __shfl_xor(vsum, d, 64);
                sm_combine(vmax, vsum, om, os);
            }
            if ((lane & 15) == 0) {
                int rowloc = wm * 64 + mf * 16 + (lane >> 4) * 4 + r;
                redm[wn][rowloc] = vmax;
                reds[wn][rowloc] = vsum;
            }
        }
    }
    __syncthreads();
    if (tid < BM) {
        float m = redm[0][tid], s = reds[0][tid];
        sm_combine(m, s, redm[1][tid], reds[1][tid]);
        partials[(size_t)(row0 + tid) * NCT + ct] = make_float2(m, s);
    }
}

// label dtype robustness: harness may hand int32 or int64 (LE). Positive labels =>
// int64 layout has zero odd words. P(8 random int32 labels all zero) ~ 1e-40.
__device__ __forceinline__ int get_label(const int* lab32, int b) {
    bool is64 = true;
    #pragma unroll
    for (int i = 1; i < 16; i += 2) is64 = is64 && (lab32[i] == 0);
    return is64 ? (int)(((const long long*)lab32)[b]) : lab32[b];
}

// ---------------- K4: per-row lse combine + exact f32 label logit -> nll ----------------
__global__ void k_row(const float* __restrict__ e, const float* __restrict__ w,
                      const int* __restrict__ labels, const float* __restrict__ rne,
                      const float* __restrict__ rnw, const float2* __restrict__ partials,
                      float* __restrict__ row_nll) {
    const int b = blockIdx.x;
    const int tid = threadIdx.x;

    float m = -INFINITY, s = 0.0f;
    for (int ctn = tid; ctn < NCT; ctn += 256) {
        float2 p = partials[(size_t)b * NCT + ctn];
        sm_combine(m, s, p.x, p.y);
    }
    #pragma unroll
    for (int d = 1; d < 64; d <<= 1) {
        float om = __shfl_xor(m, d, 64);
        float os = __shfl_xor(s, d, 64);
        sm_combine(m, s, om, os);
    }
    __shared__ float sm_[4], ss_[4], sd_[4];
    if ((tid & 63) == 0) { sm_[tid >> 6] = m; ss_[tid >> 6] = s; }

    // label dot in f32
    int lab = get_label(labels, b);
    const float* ep = e + (size_t)b * D_;
    const float* wp = w + (size_t)lab * D_;
    float dot = ep[tid] * wp[tid] + ep[tid + 256] * wp[tid + 256];
    #pragma unroll
    for (int d = 1; d < 64; d <<= 1) dot += __shfl_xor(dot, d, 64);
    if ((tid & 63) == 0) sd_[tid >> 6] = dot;
    __syncthreads();

    if (tid == 0) {
        float M = sm_[0], S = ss_[0];
        sm_combine(M, S, sm_[1], ss_[1]);
        sm_combine(M, S, sm_[2], ss_[2]);
        sm_combine(M, S, sm_[3], ss_[3]);
        float lse = M + logf(S);
        float c = (sd_[0] + sd_[1] + sd_[2] + sd_[3]) * rne[b] * rnw[lab];
        c = fminf(fmaxf(c, -1.0f), 1.0f);
        float st = sqrtf(fmaxf(1.0f - c * c, 0.0f));
        float cm = c * COS_M_ - st * SIN_M_;
        cm = (c > THRESH) ? cm : (c - MM_);
        row_nll[b] = lse - cm * S_SCALE;
    }
}

// ---------------- K5: mean ----------------
__global__ void k_mean(const float* __restrict__ row_nll, float* __restrict__ out) {
    int tid = threadIdx.x;
    float s = 0.0f;
    for (int i = tid; i < B_; i += 256) s += row_nll[i];
    #pragma unroll
    for (int d = 1; d < 64; d <<= 1) s += __shfl_xor(s, d, 64);
    __shared__ float sb[4];
    if ((tid & 63) == 0) sb[tid >> 6] = s;
    __syncthreads();
    if (tid == 0) out[0] = (sb[0] + sb[1] + sb[2] + sb[3]) / (float)B_;
}

extern "C" void kernel_launch(void* const* d_in, const int* in_sizes, int n_in,
                              void* d_out, int out_size, void* d_ws, size_t ws_size,
                              hipStream_t stream) {
    const float* e      = (const float*)d_in[0];
    const int*   labels = (const int*)d_in[1];
    const float* w      = (const float*)d_in[2];
    float* out = (float*)d_out;
    char* ws = (char*)d_ws;

    unsigned short* ebf = (unsigned short*)ws;                   // 2,097,152 B
    float* rne          = (float*)(ws + 2097152);                // 8,192 B
    float* rnw          = (float*)(ws + 2105344);                // 400,000 B
    float2* partials    = (float2*)(ws + 2505344);               // 12,812,288 B
    float* row_nll      = (float*)(ws + 15317632);               // 8,192 B

    k_norm_e<<<B_ / 4, 256, 0, stream>>>(e, ebf, rne);
    k_norm_w<<<V_ / 4, 256, 0, stream>>>(w, rnw);
    dim3 g3(B_ / BM, NCT);
    k_gemm<<<g3, 256, 0, stream>>>(ebf, w, rnw, partials);
    k_row<<<B_, 256, 0, stream>>>(e, w, labels, rne, rnw, partials, row_nll);
    k_mean<<<1, 256, 0, stream>>>(row_nll, out);
}

// Round 2
// 568.882 us; speedup vs baseline: 1.4792x; 1.4792x over previous
//
#include <hip/hip_runtime.h>
#include <hip/hip_bf16.h>
#include <math.h>

#define B_ 2048
#define D_ 512
#define V_ 100000
#define BM 128
#define BN 128
#define BK 64
#define NCT 782   // ceil(100000/128)

constexpr float S_SCALE = 64.0f;
constexpr float COS_M_ = 0.8775825618903728f;   // cos(0.5)
constexpr float SIN_M_ = 0.479425538604203f;    // sin(0.5)
constexpr float MM_    = 0.2397127693021015f;   // sin(0.5)*0.5
constexpr float THRESH = -0.8775825618903728f;  // cos(pi-0.5)
constexpr float LOG2E  = 1.4426950408889634f;
constexpr float LN2    = 0.6931471805599453f;
constexpr float S2     = 64.0f * LOG2E;         // logits scaled to base-2 domain

typedef __attribute__((ext_vector_type(8))) short short8;
typedef __attribute__((ext_vector_type(4))) float f32x4;

__device__ __forceinline__ unsigned short f2bf(float x) {
    __hip_bfloat16 h = __float2bfloat16(x);
    unsigned short u;
    __builtin_memcpy(&u, &h, 2);
    return u;
}

// swizzled ushort index within a [128][64] bf16 LDS tile: ushort idx ^= ((row&7)<<3)
__device__ __forceinline__ int swz(int row, int col) {
    return (row * BK + col) ^ ((row & 7) << 3);
}

// async global->LDS, 16B per lane; LDS dest = uniform base + lane*16
__device__ __forceinline__ void load_lds16(const unsigned short* g, unsigned short* l) {
    __builtin_amdgcn_global_load_lds(
        (const __attribute__((address_space(1))) unsigned int*)g,
        (__attribute__((address_space(3))) unsigned int*)l,
        16, 0, 0);
}

// ---------------- K1: normalize embeddings -> bf16, store rnorm_e ----------------
__global__ void k_norm_e(const float* __restrict__ e, unsigned short* __restrict__ ebf,
                         float* __restrict__ rne) {
    int row = blockIdx.x * 4 + (threadIdx.x >> 6);
    int lane = threadIdx.x & 63;
    const float4* src = (const float4*)(e + (size_t)row * D_);
    float4 a = src[lane];
    float4 b = src[lane + 64];
    float ss = a.x*a.x + a.y*a.y + a.z*a.z + a.w*a.w
             + b.x*b.x + b.y*b.y + b.z*b.z + b.w*b.w;
    #pragma unroll
    for (int d = 1; d < 64; d <<= 1) ss += __shfl_xor(ss, d, 64);
    float rn = 1.0f / fmaxf(sqrtf(ss), 1e-12f);
    ushort4* dst = (ushort4*)(ebf + (size_t)row * D_);
    dst[lane]      = make_ushort4(f2bf(a.x*rn), f2bf(a.y*rn), f2bf(a.z*rn), f2bf(a.w*rn));
    dst[lane + 64] = make_ushort4(f2bf(b.x*rn), f2bf(b.y*rn), f2bf(b.z*rn), f2bf(b.w*rn));
    if (lane == 0) rne[row] = rn;
}

// ---------------- K2: weight row rnorms (+ optional normalized bf16 weight) ----------------
__global__ void k_norm_w(const float* __restrict__ w, float* __restrict__ rnw,
                         unsigned short* __restrict__ wbf) {
    int row = blockIdx.x * 4 + (threadIdx.x >> 6);
    int lane = threadIdx.x & 63;
    const float4* src = (const float4*)(w + (size_t)row * D_);
    float4 a = src[lane];
    float4 b = src[lane + 64];
    float ss = a.x*a.x + a.y*a.y + a.z*a.z + a.w*a.w
             + b.x*b.x + b.y*b.y + b.z*b.z + b.w*b.w;
    #pragma unroll
    for (int d = 1; d < 64; d <<= 1) ss += __shfl_xor(ss, d, 64);
    float rn = 1.0f / fmaxf(sqrtf(ss), 1e-12f);
    if (wbf) {
        ushort4* dst = (ushort4*)(wbf + (size_t)row * D_);
        dst[lane]      = make_ushort4(f2bf(a.x*rn), f2bf(a.y*rn), f2bf(a.z*rn), f2bf(a.w*rn));
        dst[lane + 64] = make_ushort4(f2bf(b.x*rn), f2bf(b.y*rn), f2bf(b.z*rn), f2bf(b.w*rn));
    }
    if (lane == 0) rnw[row] = rn;
}

// combine two online-softmax states (base-2 domain), -inf-safe
__device__ __forceinline__ void sm_combine2(float& m, float& s, float om, float os) {
    float M = fmaxf(m, om);
    float ns = ((m  == -INFINITY) ? 0.0f : s  * __builtin_amdgcn_exp2f(m  - M))
             + ((om == -INFINITY) ? 0.0f : os * __builtin_amdgcn_exp2f(om - M));
    m = M; s = ns;
}

// ---------------- K3: fused GEMM + ArcFace + per-tile log2-sum-exp2 partials ----------------
// PRE=1: A,B staged via global_load_lds from pre-normalized bf16 (linear LDS,
//        pre-swizzled global source addr — m173 pattern).
// PRE=0: fallback, in-kernel f32->bf16 conversion (round-1 staging).
template <int PRE>
__global__ __launch_bounds__(256) void k_gemm(const unsigned short* __restrict__ ebf,
                                              const unsigned short* __restrict__ wbf,
                                              const float* __restrict__ w,
                                              const float* __restrict__ rnw,
                                              float2* __restrict__ partials) {
    const int rt = blockIdx.x;         // 16 row tiles
    const int ct = blockIdx.y;         // 782 col tiles
    const int row0 = rt * BM, n0 = ct * BN;
    const int tid = threadIdx.x, lane = tid & 63, wid = tid >> 6;
    const int wm = wid >> 1, wn = wid & 1;

    __shared__ __align__(16) unsigned short As[BM * BK];  // 16KB swizzled
    __shared__ __align__(16) unsigned short Bs[BN * BK];  // 16KB swizzled
    __shared__ float redm[2][BM], reds[2][BM];

    f32x4 acc[4][4];
    #pragma unroll
    for (int i = 0; i < 4; ++i)
        #pragma unroll
        for (int j = 0; j < 4; ++j)
            acc[i][j] = (f32x4){0.f, 0.f, 0.f, 0.f};

    // per-lane staging source coordinates (constant across K-steps).
    // chunk i of this wave covers linear ushort range [wid*2048+i*512, +512);
    // lane l owns 8 ushorts at p = base + l*8. LDS stays LINEAR; the swizzle
    // is applied to the GLOBAL source column so that LDS[p] == tile[r][c^((r&7)<<3)]
    // i.e. reads via swz(r,c) see tile[r][c].
    int srow[4], scol[4];
    #pragma unroll
    for (int i = 0; i < 4; ++i) {
        int p = wid * 2048 + i * 512 + lane * 8;
        int r = p >> 6;
        srow[i] = r;
        scol[i] = (p & 63) ^ ((r & 7) << 3);
    }

    for (int ks = 0; ks < D_ / BK; ++ks) {
        const int kk = ks * BK;
        if (PRE) {
            #pragma unroll
            for (int i = 0; i < 4; ++i) {
                load_lds16(ebf + (size_t)(row0 + srow[i]) * D_ + kk + scol[i],
                           As + wid * 2048 + i * 512);
                int gr = n0 + srow[i]; if (gr >= V_) gr = V_ - 1;  // dup row, masked in epilogue
                load_lds16(wbf + (size_t)gr * D_ + kk + scol[i],
                           Bs + wid * 2048 + i * 512);
            }
        } else {
            #pragma unroll
            for (int p = 0; p < 4; ++p) {
                int idx = p * 256 + tid;
                int r = idx >> 3;
                int c = (idx & 7) * 8;
                uint4 val = *(const uint4*)(ebf + (size_t)(row0 + r) * D_ + kk + c);
                *(uint4*)(As + swz(r, c)) = val;
            }
            #pragma unroll
            for (int p = 0; p < 4; ++p) {
                int idx = p * 256 + tid;
                int r = idx >> 3;
                int c = (idx & 7) * 8;
                int gr = n0 + r;
                uint4 val;
                if (gr < V_) {
                    float rn = rnw[gr];
                    const float4* src = (const float4*)(w + (size_t)gr * D_ + kk + c);
                    float4 f0 = src[0], f1 = src[1];
                    val.x = (unsigned)f2bf(f0.x*rn) | ((unsigned)f2bf(f0.y*rn) << 16);
                    val.y = (unsigned)f2bf(f0.z*rn) | ((unsigned)f2bf(f0.w*rn) << 16);
                    val.z = (unsigned)f2bf(f1.x*rn) | ((unsigned)f2bf(f1.y*rn) << 16);
                    val.w = (unsigned)f2bf(f1.z*rn) | ((unsigned)f2bf(f1.w*rn) << 16);
                } else {
                    val = make_uint4(0, 0, 0, 0);
                }
                *(uint4*)(Bs + swz(r, c)) = val;
            }
        }
        __syncthreads();
        #pragma unroll
        for (int kc = 0; kc < 2; ++kc) {
            const int kbase = kc * 32 + (lane >> 4) * 8;
            short8 af[4], bfr[4];
            #pragma unroll
            for (int mf = 0; mf < 4; ++mf) {
                int r = wm * 64 + mf * 16 + (lane & 15);
                af[mf] = *(const short8*)(As + swz(r, kbase));
            }
            #pragma unroll
            for (int nf = 0; nf < 4; ++nf) {
                int r = wn * 64 + nf * 16 + (lane & 15);
                bfr[nf] = *(const short8*)(Bs + swz(r, kbase));
            }
            #pragma unroll
            for (int mf = 0; mf < 4; ++mf)
                #pragma unroll
                for (int nf = 0; nf < 4; ++nf)
                    acc[mf][nf] = __builtin_amdgcn_mfma_f32_16x16x32_bf16(af[mf], bfr[nf], acc[mf][nf], 0, 0, 0);
        }
        __syncthreads();
    }

    // epilogue: ArcFace transform + per-row (max, sum exp2) over this tile's 128 cols.
    // two-pass: cheap fmax shfl-reduce, then one exp2 per logit, add shfl-reduce.
    #pragma unroll
    for (int mf = 0; mf < 4; ++mf) {
        #pragma unroll
        for (int r = 0; r < 4; ++r) {
            float lg[4];
            bool val[4];
            float vmax = -INFINITY;
            #pragma unroll
            for (int nf = 0; nf < 4; ++nf) {
                float cth = acc[mf][nf][r];
                int col = n0 + wn * 64 + nf * 16 + (lane & 15);
                val[nf] = col < V_;
                cth = fminf(fmaxf(cth, -1.0f), 1.0f);
                float sth = sqrtf(fmaxf(1.0f - cth * cth, 0.0f));
                float cm = cth * COS_M_ - sth * SIN_M_;
                cm = (cth > THRESH) ? cm : (cth - MM_);
                lg[nf] = cm * S2;
                if (val[nf]) vmax = fmaxf(vmax, lg[nf]);
            }
            #pragma unroll
            for (int d = 1; d < 16; d <<= 1) vmax = fmaxf(vmax, __shfl_xor(vmax, d, 64));
            float vsum = 0.0f;
            #pragma unroll
            for (int nf = 0; nf < 4; ++nf)
                if (val[nf]) vsum += __builtin_amdgcn_exp2f(lg[nf] - vmax);
            #pragma unroll
            for (int d = 1; d < 16; d <<= 1) vsum += __shfl_xor(vsum, d, 64);
            if ((lane & 15) == 0) {
                int rowloc = wm * 64 + mf * 16 + (lane >> 4) * 4 + r;
                redm[wn][rowloc] = vmax;
                reds[wn][rowloc] = vsum;
            }
        }
    }
    __syncthreads();
    if (tid < BM) {
        float m = redm[0][tid], s = reds[0][tid];
        sm_combine2(m, s, redm[1][tid], reds[1][tid]);
        partials[(size_t)(row0 + tid) * NCT + ct] = make_float2(m, s);
    }
}

// label dtype robustness: harness may hand int32 or int64 (LE). Labels in [0,V) =>
// int64 layout has zero odd words. P(8 random int32 labels all zero) ~ 1e-40.
__device__ __forceinline__ int get_label(const int* lab32, int b) {
    bool is64 = true;
    #pragma unroll
    for (int i = 1; i < 16; i += 2) is64 = is64 && (lab32[i] == 0);
    return is64 ? (int)(((const long long*)lab32)[b]) : lab32[b];
}

// ---------------- K4: per-row lse combine + exact f32 label logit -> nll ----------------
__global__ void k_row(const float* __restrict__ e, const float* __restrict__ w,
                      const int* __restrict__ labels, const float* __restrict__ rne,
                      const float* __restrict__ rnw, const float2* __restrict__ partials,
                      float* __restrict__ row_nll) {
    const int b = blockIdx.x;
    const int tid = threadIdx.x;

    float m = -INFINITY, s = 0.0f;
    for (int ctn = tid; ctn < NCT; ctn += 256) {
        float2 p = partials[(size_t)b * NCT + ctn];
        sm_combine2(m, s, p.x, p.y);
    }
    #pragma unroll
    for (int d = 1; d < 64; d <<= 1) {
        float om = __shfl_xor(m, d, 64);
        float os = __shfl_xor(s, d, 64);
        sm_combine2(m, s, om, os);
    }
    __shared__ float sm_[4], ss_[4], sd_[4];
    if ((tid & 63) == 0) { sm_[tid >> 6] = m; ss_[tid >> 6] = s; }

    // label dot in f32
    int lab = get_label(labels, b);
    const float* ep = e + (size_t)b * D_;
    const float* wp = w + (size_t)lab * D_;
    float dot = ep[tid] * wp[tid] + ep[tid + 256] * wp[tid + 256];
    #pragma unroll
    for (int d = 1; d < 64; d <<= 1) dot += __shfl_xor(dot, d, 64);
    if ((tid & 63) == 0) sd_[tid >> 6] = dot;
    __syncthreads();

    if (tid == 0) {
        float M = sm_[0], S = ss_[0];
        sm_combine2(M, S, sm_[1], ss_[1]);
        sm_combine2(M, S, sm_[2], ss_[2]);
        sm_combine2(M, S, sm_[3], ss_[3]);
        float lse = (M + __builtin_amdgcn_logf(S)) * LN2;   // v_log_f32 = log2
        float c = (sd_[0] + sd_[1] + sd_[2] + sd_[3]) * rne[b] * rnw[lab];
        c = fminf(fmaxf(c, -1.0f), 1.0f);
        float st = sqrtf(fmaxf(1.0f - c * c, 0.0f));
        float cm = c * COS_M_ - st * SIN_M_;
        cm = (c > THRESH) ? cm : (c - MM_);
        row_nll[b] = lse - cm * S_SCALE;
    }
}

// ---------------- K5: mean ----------------
__global__ void k_mean(const float* __restrict__ row_nll, float* __restrict__ out) {
    int tid = threadIdx.x;
    float s = 0.0f;
    for (int i = tid; i < B_; i += 256) s += row_nll[i];
    #pragma unroll
    for (int d = 1; d < 64; d <<= 1) s += __shfl_xor(s, d, 64);
    __shared__ float sb[4];
    if ((tid & 63) == 0) sb[tid >> 6] = s;
    __syncthreads();
    if (tid == 0) out[0] = (sb[0] + sb[1] + sb[2] + sb[3]) / (float)B_;
}

extern "C" void kernel_launch(void* const* d_in, const int* in_sizes, int n_in,
                              void* d_out, int out_size, void* d_ws, size_t ws_size,
                              hipStream_t stream) {
    const float* e      = (const float*)d_in[0];
    const int*   labels = (const int*)d_in[1];
    const float* w      = (const float*)d_in[2];
    float* out = (float*)d_out;
    char* ws = (char*)d_ws;

    // workspace layout
    unsigned short* ebf = (unsigned short*)ws;                   // 2,097,152 B
    float* rne          = (float*)(ws + 2097152);                // 8,192 B
    float* rnw          = (float*)(ws + 2105344);                // 400,000 B
    float2* partials    = (float2*)(ws + 2505344);               // 12,812,288 B
    float* row_nll      = (float*)(ws + 15317632);               // 8,192 B
    unsigned short* wbf = (unsigned short*)(ws + 15325824);      // 102,400,000 B
    const size_t NEED_PRE = 15325824 + (size_t)V_ * D_ * 2;

    const bool pre = ws_size >= NEED_PRE;

    k_norm_e<<<B_ / 4, 256, 0, stream>>>(e, ebf, rne);
    k_norm_w<<<V_ / 4, 256, 0, stream>>>(w, rnw, pre ? wbf : nullptr);
    dim3 g3(B_ / BM, NCT);
    if (pre) k_gemm<1><<<g3, 256, 0, stream>>>(ebf, wbf, w, rnw, partials);
    else     k_gemm<0><<<g3, 256, 0, stream>>>(ebf, wbf, w, rnw, partials);
    k_row<<<B_, 256, 0, stream>>>(e, w, labels, rne, rnw, partials, row_nll);
    k_mean<<<1, 256, 0, stream>>>(row_nll, out);
}

// Round 3
// 349.056 us; speedup vs baseline: 2.4107x; 1.6298x over previous
//
#include <hip/hip_runtime.h>
#include <hip/hip_bf16.h>
#include <math.h>

#define B_ 2048
#define D_ 512
#define V_ 100000
#define BM 128
#define BN 128
#define NCT 782           // ceil(100000/128)
#define NBLK (16 * NCT)   // 12512
#define NBUF 3

constexpr float S_SCALE = 64.0f;
constexpr float COS_M_ = 0.8775825618903728f;   // cos(0.5)
constexpr float SIN_M_ = 0.479425538604203f;    // sin(0.5)
constexpr float MM_    = 0.2397127693021015f;   // sin(0.5)*0.5
constexpr float THRESH = -0.8775825618903728f;  // cos(pi-0.5)
constexpr float LOG2E  = 1.4426950408889634f;
constexpr float LN2    = 0.6931471805599453f;
constexpr float S2     = 64.0f * LOG2E;         // logits in base-2 domain

typedef __attribute__((ext_vector_type(8))) short short8;
typedef __attribute__((ext_vector_type(4))) float f32x4;

__device__ __forceinline__ unsigned short f2bf(float x) {
    __hip_bfloat16 h = __float2bfloat16(x);
    unsigned short u;
    __builtin_memcpy(&u, &h, 2);
    return u;
}

__device__ __forceinline__ void load_lds16(const unsigned short* g, unsigned short* l) {
    __builtin_amdgcn_global_load_lds(
        (const __attribute__((address_space(1))) unsigned int*)g,
        (__attribute__((address_space(3))) unsigned int*)l,
        16, 0, 0);
}

// ---------------- K1: normalize embeddings -> bf16, store rnorm_e ----------------
__global__ void k_norm_e(const float* __restrict__ e, unsigned short* __restrict__ ebf,
                         float* __restrict__ rne) {
    int row = blockIdx.x * 4 + (threadIdx.x >> 6);
    int lane = threadIdx.x & 63;
    const float4* src = (const float4*)(e + (size_t)row * D_);
    float4 a = src[lane];
    float4 b = src[lane + 64];
    float ss = a.x*a.x + a.y*a.y + a.z*a.z + a.w*a.w
             + b.x*b.x + b.y*b.y + b.z*b.z + b.w*b.w;
    #pragma unroll
    for (int d = 1; d < 64; d <<= 1) ss += __shfl_xor(ss, d, 64);
    float rn = 1.0f / fmaxf(sqrtf(ss), 1e-12f);
    ushort4* dst = (ushort4*)(ebf + (size_t)row * D_);
    dst[lane]      = make_ushort4(f2bf(a.x*rn), f2bf(a.y*rn), f2bf(a.z*rn), f2bf(a.w*rn));
    dst[lane + 64] = make_ushort4(f2bf(b.x*rn), f2bf(b.y*rn), f2bf(b.z*rn), f2bf(b.w*rn));
    if (lane == 0) rne[row] = rn;
}

// ---------------- K2: weight rnorms + normalized bf16 weight ----------------
__global__ void k_norm_w(const float* __restrict__ w, float* __restrict__ rnw,
                         unsigned short* __restrict__ wbf) {
    int row = blockIdx.x * 4 + (threadIdx.x >> 6);
    int lane = threadIdx.x & 63;
    const float4* src = (const float4*)(w + (size_t)row * D_);
    float4 a = src[lane];
    float4 b = src[lane + 64];
    float ss = a.x*a.x + a.y*a.y + a.z*a.z + a.w*a.w
             + b.x*b.x + b.y*b.y + b.z*b.z + b.w*b.w;
    #pragma unroll
    for (int d = 1; d < 64; d <<= 1) ss += __shfl_xor(ss, d, 64);
    float rn = 1.0f / fmaxf(sqrtf(ss), 1e-12f);
    if (wbf) {
        ushort4* dst = (ushort4*)(wbf + (size_t)row * D_);
        dst[lane]      = make_ushort4(f2bf(a.x*rn), f2bf(a.y*rn), f2bf(a.z*rn), f2bf(a.w*rn));
        dst[lane + 64] = make_ushort4(f2bf(b.x*rn), f2bf(b.y*rn), f2bf(b.z*rn), f2bf(b.w*rn));
    }
    if (lane == 0) rnw[row] = rn;
}

// combine two online-softmax states (base-2 domain), -inf-safe
__device__ __forceinline__ void sm_combine2(float& m, float& s, float om, float os) {
    float M = fmaxf(m, om);
    float ns = ((m  == -INFINITY) ? 0.0f : s  * __builtin_amdgcn_exp2f(m  - M))
             + ((om == -INFINITY) ? 0.0f : os * __builtin_amdgcn_exp2f(om - M));
    m = M; s = ns;
}

// ---------------- K3: fused GEMM + ArcFace + per-tile log2-sum-exp2 partials ----------------
// BK=32, 3 LDS buffers, 1 raw s_barrier/step, counted vmcnt(4) (never drains the
// 2-step-ahead prefetch). LDS XOR-swizzle for 64B rows: slot ^= (row>>1)&3,
// applied on the pre-swizzled GLOBAL source (gload_lds dest stays linear).
__global__ __launch_bounds__(256, 3) void k_gemm3(const unsigned short* __restrict__ ebf,
                                                  const unsigned short* __restrict__ wbf,
                                                  float2* __restrict__ partials) {
    // XCD-contiguous work mapping: XCD x owns wi in [x*1564, (x+1)*1564)
    const int id = blockIdx.x;
    const int wi = (id & 7) * (NBLK / 8) + (id >> 3);
    const int ct = wi >> 4, rt = wi & 15;
    const int row0 = rt * BM, n0 = ct * BN;
    const int tid = threadIdx.x, lane = tid & 63, wid = tid >> 6;
    const int wm = wid >> 1, wn = wid & 1;

    __shared__ __align__(16) unsigned short lds[NBUF][8192]; // per buf: A[0..4096) B[4096..8192), [128][32] each
    __shared__ float redm[2][BM], reds[2][BM];

    f32x4 acc[4][4];
    #pragma unroll
    for (int i = 0; i < 4; ++i)
        #pragma unroll
        for (int j = 0; j < 4; ++j)
            acc[i][j] = (f32x4){0.f, 0.f, 0.f, 0.f};

    // ---- staging source precompute (constant across K-steps) ----
    // lane's linear LDS ushort pos p = j*2048 + wid*512 + lane*8 -> row r = j*64+wid*16+(lane>>2),
    // slot (p&31)>>3 = lane&3; global chunk = slot ^ ((r>>1)&3) = (lane&3) ^ ((lane>>3)&3)
    const int sch = ((lane & 3) ^ ((lane >> 3) & 3)) & 3;
    const int ra = wid * 16 + (lane >> 2);
    const unsigned short* gA0 = ebf + (size_t)(row0 + ra) * D_ + sch * 8;
    const unsigned short* gA1 = gA0 + (size_t)64 * D_;
    int gb0 = n0 + ra;      if (gb0 >= V_) gb0 = V_ - 1;   // dup row, masked in epilogue
    int gb1 = n0 + ra + 64; if (gb1 >= V_) gb1 = V_ - 1;
    const unsigned short* gB0 = wbf + (size_t)gb0 * D_ + sch * 8;
    const unsigned short* gB1 = wbf + (size_t)gb1 * D_ + sch * 8;
    const int ldsbase = wid * 512;   // ushort offset, wave-uniform

    auto STAGE = [&](int t) {
        unsigned short* Lb = &lds[t % NBUF][0];
        const int off = t * 32;
        load_lds16(gA0 + off, Lb + ldsbase);
        load_lds16(gA1 + off, Lb + 2048 + ldsbase);
        load_lds16(gB0 + off, Lb + 4096 + ldsbase);
        load_lds16(gB1 + off, Lb + 6144 + ldsbase);
    };

    // ---- ds_read byte offsets (constant across K-steps) ----
    // logical chunk = lane>>4; stored slot = chunk ^ ((r>>1)&3); (r>>1)&3 == (lane>>1)&3
    const int sA = ((lane >> 4) ^ ((lane >> 1) & 3)) & 3;
    int aoff[4], boff[4];
    #pragma unroll
    for (int mf = 0; mf < 4; ++mf) {
        int r = wm * 64 + mf * 16 + (lane & 15);
        aoff[mf] = (r * 32 + sA * 8) * 2;
    }
    #pragma unroll
    for (int nf = 0; nf < 4; ++nf) {
        int r = wn * 64 + nf * 16 + (lane & 15);
        boff[nf] = (4096 + r * 32 + sA * 8) * 2;
    }

    STAGE(0);
    STAGE(1);
    for (int t = 0; t < 16; ++t) {
        // wait own t-loads (issued at t-2) done; leave t+1's 4 in flight; then block-sync.
        if (t < 15) asm volatile("s_waitcnt vmcnt(4)\n\ts_barrier" ::: "memory");
        else        asm volatile("s_waitcnt vmcnt(0)\n\ts_barrier" ::: "memory");
        if (t + 2 < 16) STAGE(t + 2);   // buf[(t+2)%3] last read at t-1, barrier-ordered safe

        const char* Lb = (const char*)&lds[t % NBUF][0];
        short8 af[4], bfr[4];
        #pragma unroll
        for (int mf = 0; mf < 4; ++mf) af[mf] = *(const short8*)(Lb + aoff[mf]);
        #pragma unroll
        for (int nf = 0; nf < 4; ++nf) bfr[nf] = *(const short8*)(Lb + boff[nf]);
        #pragma unroll
        for (int mf = 0; mf < 4; ++mf)
            #pragma unroll
            for (int nf = 0; nf < 4; ++nf)
                acc[mf][nf] = __builtin_amdgcn_mfma_f32_16x16x32_bf16(af[mf], bfr[nf], acc[mf][nf], 0, 0, 0);
    }

    // ---- epilogue: ArcFace transform + per-row (max, sum exp2) over tile cols ----
    const int vlim = V_ - n0;   // cols with coltile < vlim are valid
    #pragma unroll
    for (int mf = 0; mf < 4; ++mf) {
        #pragma unroll
        for (int r = 0; r < 4; ++r) {
            float lg[4];
            float vmax = -INFINITY;
            #pragma unroll
            for (int nf = 0; nf < 4; ++nf) {
                float c = acc[mf][nf][r];
                int coltile = wn * 64 + nf * 16 + (lane & 15);
                c = fminf(fmaxf(c, -1.0f), 1.0f);
                float tt = fmaxf(fmaf(-c, c, 1.0f), 0.0f);
                float st = __builtin_amdgcn_sqrtf(tt);
                float cm = fmaf(c, COS_M_, -st * SIN_M_);
                cm = (c > THRESH) ? cm : (c - MM_);
                float l = cm * S2;
                lg[nf] = (coltile < vlim) ? l : -INFINITY;
                vmax = fmaxf(vmax, lg[nf]);
            }
            #pragma unroll
            for (int d = 1; d < 16; d <<= 1) vmax = fmaxf(vmax, __shfl_xor(vmax, d, 64));
            float vsum = 0.0f;
            #pragma unroll
            for (int nf = 0; nf < 4; ++nf) vsum += __builtin_amdgcn_exp2f(lg[nf] - vmax);
            #pragma unroll
            for (int d = 1; d < 16; d <<= 1) vsum += __shfl_xor(vsum, d, 64);
            if ((lane & 15) == 0) {
                int rowloc = wm * 64 + mf * 16 + (lane >> 4) * 4 + r;
                redm[wn][rowloc] = vmax;
                reds[wn][rowloc] = vsum;   // NaN only if whole half-tile invalid; discarded below
            }
        }
    }
    __syncthreads();
    if (tid < BM) {
        float m = redm[0][tid], s = reds[0][tid];
        sm_combine2(m, s, redm[1][tid], reds[1][tid]);
        partials[(size_t)(row0 + tid) * NCT + ct] = make_float2(m, s);
    }
}

// ---------------- fallback GEMM (no wbf workspace): round-2 proven path ----------------
__device__ __forceinline__ int swz64(int row, int col) {   // [128][64] ushort tile
    return (row * 64 + col) ^ ((row & 7) << 3);
}
__global__ __launch_bounds__(256) void k_gemm_fb(const unsigned short* __restrict__ ebf,
                                                 const float* __restrict__ w,
                                                 const float* __restrict__ rnw,
                                                 float2* __restrict__ partials) {
    const int rt = blockIdx.x, ct = blockIdx.y;
    const int row0 = rt * BM, n0 = ct * BN;
    const int tid = threadIdx.x, lane = tid & 63, wid = tid >> 6;
    const int wm = wid >> 1, wn = wid & 1;
    __shared__ __align__(16) unsigned short As[BM * 64];
    __shared__ __align__(16) unsigned short Bs[BN * 64];
    __shared__ float redm[2][BM], reds[2][BM];
    f32x4 acc[4][4];
    #pragma unroll
    for (int i = 0; i < 4; ++i)
        #pragma unroll
        for (int j = 0; j < 4; ++j) acc[i][j] = (f32x4){0.f, 0.f, 0.f, 0.f};
    for (int ks = 0; ks < D_ / 64; ++ks) {
        const int kk = ks * 64;
        #pragma unroll
        for (int p = 0; p < 4; ++p) {
            int idx = p * 256 + tid;
            int r = idx >> 3, c = (idx & 7) * 8;
            *(uint4*)(As + swz64(r, c)) = *(const uint4*)(ebf + (size_t)(row0 + r) * D_ + kk + c);
        }
        #pragma unroll
        for (int p = 0; p < 4; ++p) {
            int idx = p * 256 + tid;
            int r = idx >> 3, c = (idx & 7) * 8;
            int gr = n0 + r;
            uint4 val = make_uint4(0, 0, 0, 0);
            if (gr < V_) {
                float rn = rnw[gr];
                const float4* src = (const float4*)(w + (size_t)gr * D_ + kk + c);
                float4 f0 = src[0], f1 = src[1];
                val.x = (unsigned)f2bf(f0.x*rn) | ((unsigned)f2bf(f0.y*rn) << 16);
                val.y = (unsigned)f2bf(f0.z*rn) | ((unsigned)f2bf(f0.w*rn) << 16);
                val.z = (unsigned)f2bf(f1.x*rn) | ((unsigned)f2bf(f1.y*rn) << 16);
                val.w = (unsigned)f2bf(f1.z*rn) | ((unsigned)f2bf(f1.w*rn) << 16);
            }
            *(uint4*)(Bs + swz64(r, c)) = val;
        }
        __syncthreads();
        #pragma unroll
        for (int kc = 0; kc < 2; ++kc) {
            const int kbase = kc * 32 + (lane >> 4) * 8;
            short8 af[4], bfr[4];
            #pragma unroll
            for (int mf = 0; mf < 4; ++mf) af[mf] = *(const short8*)(As + swz64(wm * 64 + mf * 16 + (lane & 15), kbase));
            #pragma unroll
            for (int nf = 0; nf < 4; ++nf) bfr[nf] = *(const short8*)(Bs + swz64(wn * 64 + nf * 16 + (lane & 15), kbase));
            #pragma unroll
            for (int mf = 0; mf < 4; ++mf)
                #pragma unroll
                for (int nf = 0; nf < 4; ++nf)
                    acc[mf][nf] = __builtin_amdgcn_mfma_f32_16x16x32_bf16(af[mf], bfr[nf], acc[mf][nf], 0, 0, 0);
        }
        __syncthreads();
    }
    const int vlim = V_ - n0;
    #pragma unroll
    for (int mf = 0; mf < 4; ++mf) {
        #pragma unroll
        for (int r = 0; r < 4; ++r) {
            float lg[4];
            float vmax = -INFINITY;
            #pragma unroll
            for (int nf = 0; nf < 4; ++nf) {
                float c = acc[mf][nf][r];
                int coltile = wn * 64 + nf * 16 + (lane & 15);
                c = fminf(fmaxf(c, -1.0f), 1.0f);
                float tt = fmaxf(fmaf(-c, c, 1.0f), 0.0f);
                float st = __builtin_amdgcn_sqrtf(tt);
                float cm = fmaf(c, COS_M_, -st * SIN_M_);
                cm = (c > THRESH) ? cm : (c - MM_);
                float l = cm * S2;
                lg[nf] = (coltile < vlim) ? l : -INFINITY;
                vmax = fmaxf(vmax, lg[nf]);
            }
            #pragma unroll
            for (int d = 1; d < 16; d <<= 1) vmax = fmaxf(vmax, __shfl_xor(vmax, d, 64));
            float vsum = 0.0f;
            #pragma unroll
            for (int nf = 0; nf < 4; ++nf) vsum += __builtin_amdgcn_exp2f(lg[nf] - vmax);
            #pragma unroll
            for (int d = 1; d < 16; d <<= 1) vsum += __shfl_xor(vsum, d, 64);
            if ((lane & 15) == 0) {
                int rowloc = wm * 64 + mf * 16 + (lane >> 4) * 4 + r;
                redm[wn][rowloc] = vmax;
                reds[wn][rowloc] = vsum;
            }
        }
    }
    __syncthreads();
    if (tid < BM) {
        float m = redm[0][tid], s = reds[0][tid];
        sm_combine2(m, s, redm[1][tid], reds[1][tid]);
        partials[(size_t)(row0 + tid) * NCT + ct] = make_float2(m, s);
    }
}

// label dtype robustness: harness may hand int32 or int64 (LE).
__device__ __forceinline__ int get_label(const int* lab32, int b) {
    bool is64 = true;
    #pragma unroll
    for (int i = 1; i < 16; i += 2) is64 = is64 && (lab32[i] == 0);
    return is64 ? (int)(((const long long*)lab32)[b]) : lab32[b];
}

// ---------------- K4: per-row lse combine + exact f32 label logit -> nll ----------------
__global__ void k_row(const float* __restrict__ e, const float* __restrict__ w,
                      const int* __restrict__ labels, const float* __restrict__ rne,
                      const float* __restrict__ rnw, const float2* __restrict__ partials,
                      float* __restrict__ row_nll) {
    const int b = blockIdx.x;
    const int tid = threadIdx.x;

    float m = -INFINITY, s = 0.0f;
    for (int ctn = tid; ctn < NCT; ctn += 256) {
        float2 p = partials[(size_t)b * NCT + ctn];
        sm_combine2(m, s, p.x, p.y);
    }
    #pragma unroll
    for (int d = 1; d < 64; d <<= 1) {
        float om = __shfl_xor(m, d, 64);
        float os = __shfl_xor(s, d, 64);
        sm_combine2(m, s, om, os);
    }
    __shared__ float sm_[4], ss_[4], sd_[4];
    if ((tid & 63) == 0) { sm_[tid >> 6] = m; ss_[tid >> 6] = s; }

    int lab = get_label(labels, b);
    const float* ep = e + (size_t)b * D_;
    const float* wp = w + (size_t)lab * D_;
    float dot = ep[tid] * wp[tid] + ep[tid + 256] * wp[tid + 256];
    #pragma unroll
    for (int d = 1; d < 64; d <<= 1) dot += __shfl_xor(dot, d, 64);
    if ((tid & 63) == 0) sd_[tid >> 6] = dot;
    __syncthreads();

    if (tid == 0) {
        float M = sm_[0], S = ss_[0];
        sm_combine2(M, S, sm_[1], ss_[1]);
        sm_combine2(M, S, sm_[2], ss_[2]);
        sm_combine2(M, S, sm_[3], ss_[3]);
        float lse = (M + __builtin_amdgcn_logf(S)) * LN2;   // v_log_f32 = log2
        float c = (sd_[0] + sd_[1] + sd_[2] + sd_[3]) * rne[b] * rnw[lab];
        c = fminf(fmaxf(c, -1.0f), 1.0f);
        float st = sqrtf(fmaxf(1.0f - c * c, 0.0f));
        float cm = c * COS_M_ - st * SIN_M_;
        cm = (c > THRESH) ? cm : (c - MM_);
        row_nll[b] = lse - cm * S_SCALE;
    }
}

// ---------------- K5: mean ----------------
__global__ void k_mean(const float* __restrict__ row_nll, float* __restrict__ out) {
    int tid = threadIdx.x;
    float s = 0.0f;
    for (int i = tid; i < B_; i += 256) s += row_nll[i];
    #pragma unroll
    for (int d = 1; d < 64; d <<= 1) s += __shfl_xor(s, d, 64);
    __shared__ float sb[4];
    if ((tid & 63) == 0) sb[tid >> 6] = s;
    __syncthreads();
    if (tid == 0) out[0] = (sb[0] + sb[1] + sb[2] + sb[3]) / (float)B_;
}

extern "C" void kernel_launch(void* const* d_in, const int* in_sizes, int n_in,
                              void* d_out, int out_size, void* d_ws, size_t ws_size,
                              hipStream_t stream) {
    const float* e      = (const float*)d_in[0];
    const int*   labels = (const int*)d_in[1];
    const float* w      = (const float*)d_in[2];
    float* out = (float*)d_out;
    char* ws = (char*)d_ws;

    unsigned short* ebf = (unsigned short*)ws;                   // 2,097,152 B
    float* rne          = (float*)(ws + 2097152);                // 8,192 B
    float* rnw          = (float*)(ws + 2105344);                // 400,000 B
    float2* partials    = (float2*)(ws + 2505344);               // 12,812,288 B
    float* row_nll      = (float*)(ws + 15317632);               // 8,192 B
    unsigned short* wbf = (unsigned short*)(ws + 15325824);      // 102,400,000 B
    const size_t NEED_PRE = 15325824 + (size_t)V_ * D_ * 2;

    const bool pre = ws_size >= NEED_PRE;

    k_norm_e<<<B_ / 4, 256, 0, stream>>>(e, ebf, rne);
    k_norm_w<<<V_ / 4, 256, 0, stream>>>(w, rnw, pre ? wbf : nullptr);
    if (pre) {
        k_gemm3<<<NBLK, 256, 0, stream>>>(ebf, wbf, partials);
    } else {
        dim3 g3(B_ / BM, NCT);
        k_gemm_fb<<<g3, 256, 0, stream>>>(ebf, w, rnw, partials);
    }
    k_row<<<B_, 256, 0, stream>>>(e, w, labels, rne, rnw, partials, row_nll);
    k_mean<<<1, 256, 0, stream>>>(row_nll, out);
}